// Round 10
// baseline (54.038 us; speedup 1.0000x reference)
//
#include <hip/hip_runtime.h>
#include <math.h>

// TopoBrainPhysical fused forward, round 10: COMPACT-LOOP rewrite (I$ theory).
// R6/R8/R9 all plateau at ~50us despite large operand-path changes; the
// common trait is 16-20KB fully-unrolled bodies -> I-cache thrash hypothesis.
// This round: both hot kernels become short rolled loops (#pragma unroll 1,
// dynamic LDS addressing -- legal; register arrays stay statically indexed).
// k2 uses precomputed fused matrices M_cell = nw2 . rw1_cell (24x24/cell,
// built by 19 setup blocks appended to k1's grid) so its whole body is one
// 24-iter loop. M cell stride padded to 580 floats -> the 4 lane-groups'
// reads land on disjoint banks.

#define PI_F 3.14159265358979323846f

__device__ __forceinline__ float fast_tanh(float v) {
    float e = __expf(2.0f * v);
    return 1.0f - 2.0f * __builtin_amdgcn_rcpf(e + 1.0f);
}

// butterfly sum over the 4 lanes of a quad; all lanes get the total.
__device__ __forceinline__ float quad_sum(float x) {
    x += __int_as_float(__builtin_amdgcn_update_dpp(
             0, __float_as_int(x), 0xB1, 0xF, 0xF, true)); // {1,0,3,2}
    x += __int_as_float(__builtin_amdgcn_update_dpp(
             0, __float_as_int(x), 0x4E, 0xF, 0xF, true)); // {2,3,0,1}
    return x;
}

// ===================== kernel 1 (+ appended setup blocks) =====================
// LDS float layout:
// E1P[24][8]@0 (per k: ew1[0..3][k], eb1[k], pad3)   192
// EW2[24][24]@192   EB2[24]@768   EW3T[3][24]@792   EB3[3]@864  -> 880 total
#define K1_LDS 880
// ws layout: [0, B*20)  per-element {z(4), mc(8), mw(8)}  (AoS)
//            [B*20, +4608) M_cell[8][24][24]   [+4608, +4632) tinit[24]

extern "C" __global__ void __launch_bounds__(256, 2)
topo_k1(const float* __restrict__ x,
        const float* __restrict__ ew1, const float* __restrict__ eb1,
        const float* __restrict__ ew2, const float* __restrict__ eb2,
        const float* __restrict__ ew3, const float* __restrict__ eb3,
        const float* __restrict__ alog, const float* __restrict__ rlog,
        const float* __restrict__ nw2, const float* __restrict__ nb2,
        const float* __restrict__ rw1, const float* __restrict__ rb1,
        float* __restrict__ ws, int B)
{
    const int nb1b = (B + 255) >> 8;

    // ---------------- appended setup blocks: build M_cell and tinit --------
    if ((int)blockIdx.x >= nb1b) {
        const int gid = ((int)blockIdx.x - nb1b) * 256 + (int)threadIdx.x;
        float* M = ws + (size_t)B * 20;
        if (gid < 4608) {
            const int cell = gid / 576, rem = gid - cell * 576;
            const int j = rem / 24, j2 = rem - j * 24;
            float s = 0.0f;
            #pragma unroll
            for (int d = 0; d < 12; ++d)
                s += nw2[j * 12 + d] * rw1[(cell * 12 + d) * 24 + j2];
            M[gid] = s;
        } else if (gid < 4632) {
            const int j2 = gid - 4608;
            float s = rb1[j2];
            for (int i = 0; i < 96; ++i)
                s += nb2[i % 12] * rw1[i * 24 + j2];
            M[4608 + j2] = s;
        }
        return;
    }

    __shared__ float wf[K1_LDS];
    const float4* wq = reinterpret_cast<const float4*>(wf);
    {
        const int tt = threadIdx.x;
        for (int i = tt; i < 24; i += 256) {
            wf[i * 8 + 0] = ew1[i];
            wf[i * 8 + 1] = ew1[24 + i];
            wf[i * 8 + 2] = ew1[48 + i];
            wf[i * 8 + 3] = ew1[72 + i];
            wf[i * 8 + 4] = eb1[i];
        }
        for (int i = tt; i < 576; i += 256) wf[192 + i] = ew2[i];
        for (int i = tt; i < 24;  i += 256) wf[768 + i] = eb2[i];
        for (int i = tt; i < 72;  i += 256) wf[792 + (i % 3) * 24 + (i / 3)] = ew3[i];
        for (int i = tt; i < 3;   i += 256) wf[864 + i] = eb3[i];
    }
    __syncthreads();

    const int b = blockIdx.x * blockDim.x + threadIdx.x;
    if (b >= B) return;

    const float4 xv = *reinterpret_cast<const float4*>(x + (size_t)b * 60 + 56);

    // ---- encoder L1 fused into L2 loop (zt_k is a scalar) ----
    float a2[24];
    #pragma unroll
    for (int c = 0; c < 6; ++c) {
        float4 b4 = wq[192 / 4 + c];
        a2[c*4+0] = b4.x; a2[c*4+1] = b4.y; a2[c*4+2] = b4.z; a2[c*4+3] = b4.w;
    }
    #pragma unroll 1
    for (int k = 0; k < 24; ++k) {
        float4 p  = wq[2 * k];
        float4 p2 = wq[2 * k + 1];
        const float zk = fast_tanh(p2.x + xv.x*p.x + xv.y*p.y + xv.z*p.z + xv.w*p.w);
        const int rr = 48 + k * 6;   // EW2 row k (float4 index)
        float4 r0 = wq[rr+0], r1 = wq[rr+1], r2 = wq[rr+2];
        float4 r3 = wq[rr+3], r4 = wq[rr+4], r5 = wq[rr+5];
        a2[0]+=zk*r0.x; a2[1]+=zk*r0.y; a2[2]+=zk*r0.z; a2[3]+=zk*r0.w;
        a2[4]+=zk*r1.x; a2[5]+=zk*r1.y; a2[6]+=zk*r1.z; a2[7]+=zk*r1.w;
        a2[8]+=zk*r2.x; a2[9]+=zk*r2.y; a2[10]+=zk*r2.z; a2[11]+=zk*r2.w;
        a2[12]+=zk*r3.x; a2[13]+=zk*r3.y; a2[14]+=zk*r3.z; a2[15]+=zk*r3.w;
        a2[16]+=zk*r4.x; a2[17]+=zk*r4.y; a2[18]+=zk*r4.z; a2[19]+=zk*r4.w;
        a2[20]+=zk*r5.x; a2[21]+=zk*r5.y; a2[22]+=zk*r5.z; a2[23]+=zk*r5.w;
    }
    float zt2[24];
    #pragma unroll
    for (int j = 0; j < 24; ++j) zt2[j] = fast_tanh(a2[j]);

    // ---- encoder L3 (24x3, transposed; static tail) ----
    float z0 = wf[864], z1 = wf[865], z2 = wf[866];
    #pragma unroll
    for (int c = 0; c < 6; ++c) {
        float4 v0 = wq[198 + c], v1 = wq[204 + c], v2 = wq[210 + c];
        z0 += zt2[c*4+0]*v0.x + zt2[c*4+1]*v0.y + zt2[c*4+2]*v0.z + zt2[c*4+3]*v0.w;
        z1 += zt2[c*4+0]*v1.x + zt2[c*4+1]*v1.y + zt2[c*4+2]*v1.z + zt2[c*4+3]*v1.w;
        z2 += zt2[c*4+0]*v2.x + zt2[c*4+1]*v2.y + zt2[c*4+2]*v2.z + zt2[c*4+3]*v2.w;
    }

    // ---- normalized adjacency (wave-uniform scalar reads) ----
    float ang[4][4];
    {
        float m = fmaxf(fmaxf(alog[0], alog[1]), fmaxf(alog[2], alog[3]));
        float e0 = __expf(alog[0] - m), e1 = __expf(alog[1] - m);
        float e2 = __expf(alog[2] - m), e3 = __expf(alog[3] - m);
        float s = e0 + e1 + e2 + e3;
        float sm[4] = { e0 / s, e1 / s, e2 / s, e3 / s };
        #pragma unroll
        for (int i = 0; i < 4; ++i) {
            const int jn = (i + 3) & 3, jp = (i + 1) & 3;
            float inv = 1.0f / fmaxf(sm[jn] + sm[jp], 1e-6f);
            #pragma unroll
            for (int j = 0; j < 4; ++j) {
                float adj = (j == jn || j == jp) ? 1.0f : 0.0f;
                ang[i][j] = sm[j] * adj * inv;
            }
        }
    }
    float rad[2][2];
    {
        float m = fmaxf(rlog[0], rlog[1]);
        float f0 = __expf(rlog[0] - m), f1 = __expf(rlog[1] - m);
        float fs = f0 + f1;
        float sm0 = f0 / fs, sm1 = f1 / fs;
        rad[0][0] = 0.0f; rad[0][1] = sm1 / fmaxf(sm1, 1e-6f);
        rad[1][1] = 0.0f; rad[1][0] = sm0 / fmaxf(sm0, 1e-6f);
    }

    // ---- bilinear corners ----
    const float r = 1.0f / (1.0f + __expf(-z0));
    const float p = (z1 + PI_F) / (2.0f * PI_F) * 4.0f;
    const float r0f = truncf(r), p0f = truncf(p);
    const float dr = r - r0f, dp = p - p0f;
    const int r0i = (int)r0f, p0i = (int)p0f;

    const float w0c = (1.0f - dr) * (1.0f - dp);
    const float w1c = (1.0f - dr) * dp;
    const float w2c = dr * (1.0f - dp);
    const float w3c = dr * dp;

    const int ri0 = min(r0i, 1);
    const int ri2 = min(r0i + 1, 1);
    const int pi0 = p0i & 3;
    const int pi1 = (p0i + 1) & 3;

    const int c0 = ri0 * 4 + pi0, c1 = ri0 * 4 + pi1;
    const int c2 = ri2 * 4 + pi0, c3 = ri2 * 4 + pi1;

    float cnt[8], wsum[8];
    #pragma unroll
    for (int n = 0; n < 8; ++n) {
        float cm = 0.0f, cw = 0.0f;
        if (c0 == n && w0c > 0.0f) { cm += 1.0f; cw += w0c; }
        if (c1 == n && w1c > 0.0f) { cm += 1.0f; cw += w1c; }
        if (c2 == n && w2c > 0.0f) { cm += 1.0f; cw += w2c; }
        if (c3 == n && w3c > 0.0f) { cm += 1.0f; cw += w3c; }
        cnt[n] = cm; wsum[n] = cw;
    }
    float mc[8], mw[8];
    #pragma unroll
    for (int n = 0; n < 8; ++n) {
        float ac = cnt[n], aw = wsum[n];
        #pragma unroll
        for (int j = 0; j < 4; ++j) {
            const float g = ang[n >> 1][j];
            ac += g * cnt[2 * j + (n & 1)];
            aw += g * wsum[2 * j + (n & 1)];
        }
        #pragma unroll
        for (int j = 0; j < 2; ++j) {
            const float g = rad[n >> 2][j];
            ac += g * cnt[4 * j + (n & 3)];
            aw += g * wsum[4 * j + (n & 3)];
        }
        mc[n] = ac; mw[n] = aw;
    }

    // ---- AoS store: 20 floats per element ----
    float* wp = ws + (size_t)b * 20;
    float4 v0; v0.x = z0;    v0.y = z1;    v0.z = z2;    v0.w = 0.0f;
    float4 v1; v1.x = mc[0]; v1.y = mc[1]; v1.z = mc[2]; v1.w = mc[3];
    float4 v2; v2.x = mc[4]; v2.y = mc[5]; v2.z = mc[6]; v2.w = mc[7];
    float4 v3; v3.x = mw[0]; v3.y = mw[1]; v3.z = mw[2]; v3.w = mw[3];
    float4 v4; v4.x = mw[4]; v4.y = mw[5]; v4.z = mw[6]; v4.w = mw[7];
    reinterpret_cast<float4*>(wp)[0] = v0;
    reinterpret_cast<float4*>(wp)[1] = v1;
    reinterpret_cast<float4*>(wp)[2] = v2;
    reinterpret_cast<float4*>(wp)[3] = v3;
    reinterpret_cast<float4*>(wp)[4] = v4;
}

// ===================== kernel 2 =====================
// LDS float layout:
// PK[24][8]@0 (nw1[0..3][j], nb1[j], pad3)                 192
// M: 8 cells, stride 580 (24x24 row-major + pad) @192      4640
//   (stride 580: 580%16==4 -> the 4 lane-groups' cell reads hit
//    disjoint bank groups {0,8,16,24}+{4,12,20,28})
// tinit[24]@4832  RW2[24][4]@4856  RB2[4]@4952  -> 4956 floats (19.8KB)
#define K2_LDS 4956

extern "C" __global__ void __launch_bounds__(256)
topo_k2(const float* __restrict__ ws,
        const float* __restrict__ nw1, const float* __restrict__ nb1,
        const float* __restrict__ rw2, const float* __restrict__ rb2,
        float* __restrict__ out, int B)
{
    __shared__ float wf[K2_LDS];
    const float4* wq = reinterpret_cast<const float4*>(wf);
    {
        const int tt = threadIdx.x;
        const float* Msrc = ws + (size_t)B * 20;
        for (int i = tt; i < 4608; i += 256) {
            const int cell = i / 576, rem = i - cell * 576;
            wf[192 + cell * 580 + rem] = Msrc[i];
        }
        for (int i = tt; i < 24; i += 256) wf[4832 + i] = Msrc[4608 + i];
        for (int i = tt; i < 24; i += 256) {
            wf[i * 8 + 0] = nw1[i];
            wf[i * 8 + 1] = nw1[24 + i];
            wf[i * 8 + 2] = nw1[48 + i];
            wf[i * 8 + 3] = nw1[72 + i];
            wf[i * 8 + 4] = nb1[i];
        }
        for (int i = tt; i < 96; i += 256) wf[4856 + i] = rw2[i];
        for (int i = tt; i < 4;  i += 256) wf[4952 + i] = rb2[i];
    }
    __syncthreads();

    const int tid  = blockIdx.x * blockDim.x + threadIdx.x;
    const int lane = tid & 3;           // owns cells 2*lane (A), 2*lane+1 (B)
    const int b    = tid >> 2;
    if (b >= B) return;

    const float* wp = ws + (size_t)b * 20;
    const float4 zv = *reinterpret_cast<const float4*>(wp);
    const float2 mc2 = *reinterpret_cast<const float2*>(wp + 4 + 2 * lane);
    const float2 mw2 = *reinterpret_cast<const float2*>(wp + 12 + 2 * lane);
    const float z0 = zv.x, z1 = zv.y, z2 = zv.z;
    const float mcA = mc2.x, mcB = mc2.y, mwA = mw2.x, mwB = mw2.y;

    // float4 bases of this lane's two M cells (580/4 = 145)
    const int mAq = 48 + (2 * lane) * 145;
    const int mBq = mAq + 145;

    float t[24];
    #pragma unroll
    for (int j = 0; j < 24; ++j) t[j] = 0.0f;

    // ---- the entire node MLP + readout-l1: one compact 24-iter loop ----
    #pragma unroll 1
    for (int j = 0; j < 24; ++j) {
        float4 pk  = wq[2 * j];
        float4 pk2 = wq[2 * j + 1];
        const float q  = z0 * pk.x + z1 * pk.y + z2 * pk.z;
        const float hA = fast_tanh(pk2.x + mcA * q + mwA * pk.w);
        const float hB = fast_tanh(pk2.x + mcB * q + mwB * pk.w);
        const int ra = mAq + j * 6, rb = mBq + j * 6;
        float4 a0 = wq[ra+0], a1 = wq[ra+1], a2v = wq[ra+2];
        float4 a3 = wq[ra+3], a4 = wq[ra+4], a5  = wq[ra+5];
        float4 b0 = wq[rb+0], b1 = wq[rb+1], b2v = wq[rb+2];
        float4 b3 = wq[rb+3], b4 = wq[rb+4], b5  = wq[rb+5];
        t[0]  += hA*a0.x  + hB*b0.x;  t[1]  += hA*a0.y  + hB*b0.y;
        t[2]  += hA*a0.z  + hB*b0.z;  t[3]  += hA*a0.w  + hB*b0.w;
        t[4]  += hA*a1.x  + hB*b1.x;  t[5]  += hA*a1.y  + hB*b1.y;
        t[6]  += hA*a1.z  + hB*b1.z;  t[7]  += hA*a1.w  + hB*b1.w;
        t[8]  += hA*a2v.x + hB*b2v.x; t[9]  += hA*a2v.y + hB*b2v.y;
        t[10] += hA*a2v.z + hB*b2v.z; t[11] += hA*a2v.w + hB*b2v.w;
        t[12] += hA*a3.x  + hB*b3.x;  t[13] += hA*a3.y  + hB*b3.y;
        t[14] += hA*a3.z  + hB*b3.z;  t[15] += hA*a3.w  + hB*b3.w;
        t[16] += hA*a4.x  + hB*b4.x;  t[17] += hA*a4.y  + hB*b4.y;
        t[18] += hA*a4.z  + hB*b4.z;  t[19] += hA*a4.w  + hB*b4.w;
        t[20] += hA*a5.x  + hB*b5.x;  t[21] += hA*a5.y  + hB*b5.y;
        t[22] += hA*a5.z  + hB*b5.z;  t[23] += hA*a5.w  + hB*b5.w;
    }

    // ---- reduce across the 4 lanes (8 cells), add tinit (includes rb1) ----
    #pragma unroll
    for (int j = 0; j < 24; ++j) t[j] = quad_sum(t[j]) + wf[4832 + j];

    // ---- readout layer 2 (redundant in quad; lane 0 stores) ----
    float4 ob = wq[1238];
    float o0 = ob.x, o1 = ob.y, o2 = ob.z, o3 = ob.w;
    #pragma unroll
    for (int j = 0; j < 24; ++j) {
        const float tv = fast_tanh(t[j]);
        float4 rv = wq[1214 + j];
        o0 += tv * rv.x; o1 += tv * rv.y; o2 += tv * rv.z; o3 += tv * rv.w;
    }
    if (lane == 0) {
        float4 ov; ov.x = o0; ov.y = o1; ov.z = o2; ov.w = o3;
        *reinterpret_cast<float4*>(out + (size_t)b * 4) = ov;
    }
}

// ===================== fallback fused kernel (R8-verbatim) =====================
extern "C" __global__ void __launch_bounds__(256, 2)
topo_fused(const float* __restrict__ x,
           const float* __restrict__ ew1, const float* __restrict__ eb1,
           const float* __restrict__ ew2, const float* __restrict__ eb2,
           const float* __restrict__ ew3, const float* __restrict__ eb3,
           const float* __restrict__ nw1, const float* __restrict__ nb1,
           const float* __restrict__ nw2, const float* __restrict__ nb2,
           const float* __restrict__ alog, const float* __restrict__ rlog,
           const float* __restrict__ rw1, const float* __restrict__ rb1,
           const float* __restrict__ rw2, const float* __restrict__ rb2,
           float* __restrict__ out, int B)
{
    const int b = blockIdx.x * blockDim.x + threadIdx.x;
    if (b >= B) return;

    float ang[4][4];
    {
        float m = fmaxf(fmaxf(alog[0], alog[1]), fmaxf(alog[2], alog[3]));
        float e0 = __expf(alog[0] - m), e1 = __expf(alog[1] - m);
        float e2 = __expf(alog[2] - m), e3 = __expf(alog[3] - m);
        float s = e0 + e1 + e2 + e3;
        float sm[4] = { e0 / s, e1 / s, e2 / s, e3 / s };
        #pragma unroll
        for (int i = 0; i < 4; ++i) {
            const int jn = (i + 3) & 3, jp = (i + 1) & 3;
            float inv = 1.0f / fmaxf(sm[jn] + sm[jp], 1e-6f);
            #pragma unroll
            for (int j = 0; j < 4; ++j) {
                float adj = (j == jn || j == jp) ? 1.0f : 0.0f;
                ang[i][j] = sm[j] * adj * inv;
            }
        }
    }
    float rad[2][2];
    {
        float m = fmaxf(rlog[0], rlog[1]);
        float f0 = __expf(rlog[0] - m), f1 = __expf(rlog[1] - m);
        float fs = f0 + f1;
        float sm0 = f0 / fs, sm1 = f1 / fs;
        rad[0][0] = 0.0f; rad[0][1] = sm1 / fmaxf(sm1, 1e-6f);
        rad[1][1] = 0.0f; rad[1][0] = sm0 / fmaxf(sm0, 1e-6f);
    }

    const float4 xv = *reinterpret_cast<const float4*>(x + (size_t)b * 60 + 56);
    float zt[24];
    #pragma unroll
    for (int j = 0; j < 24; ++j) {
        float a = eb1[j];
        a += xv.x * ew1[j];
        a += xv.y * ew1[24 + j];
        a += xv.z * ew1[48 + j];
        a += xv.w * ew1[72 + j];
        zt[j] = fast_tanh(a);
    }
    float z0 = eb3[0], z1 = eb3[1], z2 = eb3[2];
    #pragma unroll
    for (int j = 0; j < 24; ++j) {
        float a = eb2[j];
        #pragma unroll
        for (int k = 0; k < 24; ++k) a += zt[k] * ew2[k * 24 + j];
        const float z2t = fast_tanh(a);
        z0 += z2t * ew3[j * 3 + 0];
        z1 += z2t * ew3[j * 3 + 1];
        z2 += z2t * ew3[j * 3 + 2];
    }

    const float r = 1.0f / (1.0f + __expf(-z0));
    const float p = (z1 + PI_F) / (2.0f * PI_F) * 4.0f;
    const float r0f = truncf(r), p0f = truncf(p);
    const float dr = r - r0f, dp = p - p0f;
    const int r0i = (int)r0f, p0i = (int)p0f;
    const float w0c = (1.0f - dr) * (1.0f - dp);
    const float w1c = (1.0f - dr) * dp;
    const float w2c = dr * (1.0f - dp);
    const float w3c = dr * dp;
    const int ri0 = min(r0i, 1);
    const int ri2 = min(r0i + 1, 1);
    const int pi0 = p0i & 3;
    const int pi1 = (p0i + 1) & 3;
    const int c0 = ri0 * 4 + pi0, c1 = ri0 * 4 + pi1;
    const int c2 = ri2 * 4 + pi0, c3 = ri2 * 4 + pi1;

    float cnt[8], wsum[8];
    #pragma unroll
    for (int n = 0; n < 8; ++n) {
        float cm = 0.0f, cw = 0.0f;
        if (c0 == n && w0c > 0.0f) { cm += 1.0f; cw += w0c; }
        if (c1 == n && w1c > 0.0f) { cm += 1.0f; cw += w1c; }
        if (c2 == n && w2c > 0.0f) { cm += 1.0f; cw += w2c; }
        if (c3 == n && w3c > 0.0f) { cm += 1.0f; cw += w3c; }
        cnt[n] = cm; wsum[n] = cw;
    }
    float mc[8], mw[8];
    #pragma unroll
    for (int n = 0; n < 8; ++n) {
        float ac = cnt[n], aw = wsum[n];
        #pragma unroll
        for (int j = 0; j < 4; ++j) {
            const float g = ang[n >> 1][j];
            ac += g * cnt[2 * j + (n & 1)];
            aw += g * wsum[2 * j + (n & 1)];
        }
        #pragma unroll
        for (int j = 0; j < 2; ++j) {
            const float g = rad[n >> 2][j];
            ac += g * cnt[4 * j + (n & 3)];
            aw += g * wsum[4 * j + (n & 3)];
        }
        mc[n] = ac; mw[n] = aw;
    }

    float t[24];
    #pragma unroll
    for (int j = 0; j < 24; ++j) t[j] = rb1[j];
    #pragma unroll
    for (int n = 0; n < 8; ++n) {
        const float f0 = mc[n] * z0, f1 = mc[n] * z1, f2 = mc[n] * z2;
        float ho[12];
        #pragma unroll
        for (int d = 0; d < 12; ++d) ho[d] = nb2[d];
        #pragma unroll
        for (int j = 0; j < 24; ++j) {
            const float hj = fast_tanh(nb1[j] + f0 * nw1[j] + f1 * nw1[24 + j]
                                       + f2 * nw1[48 + j] + mw[n] * nw1[72 + j]);
            #pragma unroll
            for (int d = 0; d < 12; ++d) ho[d] += hj * nw2[j * 12 + d];
        }
        #pragma unroll
        for (int d = 0; d < 12; ++d) {
            const int rbase = (n * 12 + d) * 24;
            #pragma unroll
            for (int j2 = 0; j2 < 24; ++j2) t[j2] += ho[d] * rw1[rbase + j2];
        }
    }

    float o0 = rb2[0], o1 = rb2[1], o2 = rb2[2], o3 = rb2[3];
    #pragma unroll
    for (int j = 0; j < 24; ++j) {
        const float tt = fast_tanh(t[j]);
        o0 += tt * rw2[j * 4 + 0];
        o1 += tt * rw2[j * 4 + 1];
        o2 += tt * rw2[j * 4 + 2];
        o3 += tt * rw2[j * 4 + 3];
    }
    float4 ov; ov.x = o0; ov.y = o1; ov.z = o2; ov.w = o3;
    *reinterpret_cast<float4*>(out + (size_t)b * 4) = ov;
}

extern "C" void kernel_launch(void* const* d_in, const int* in_sizes, int n_in,
                              void* d_out, int out_size, void* d_ws, size_t ws_size,
                              hipStream_t stream) {
    const float* x    = (const float*)d_in[0];
    const float* ew1  = (const float*)d_in[1];
    const float* eb1  = (const float*)d_in[2];
    const float* ew2  = (const float*)d_in[3];
    const float* eb2  = (const float*)d_in[4];
    const float* ew3  = (const float*)d_in[5];
    const float* eb3  = (const float*)d_in[6];
    const float* nw1  = (const float*)d_in[7];
    const float* nb1  = (const float*)d_in[8];
    const float* nw2  = (const float*)d_in[9];
    const float* nb2  = (const float*)d_in[10];
    const float* alog = (const float*)d_in[11];
    const float* rlog = (const float*)d_in[12];
    const float* rw1  = (const float*)d_in[13];
    const float* rb1  = (const float*)d_in[14];
    const float* rw2  = (const float*)d_in[15];
    const float* rb2  = (const float*)d_in[16];
    float* out = (float*)d_out;

    const int B = in_sizes[0] / 60;   // x is (B, 15, 4)
    const size_t ws_needed = ((size_t)B * 20 + 4632) * sizeof(float);

    if (ws_size >= ws_needed) {
        float* ws = (float*)d_ws;
        const int nb1b = (B + 255) / 256;
        const int g1 = nb1b + 19;                 // + setup blocks (4632 entries)
        topo_k1<<<g1, 256, 0, stream>>>(x, ew1, eb1, ew2, eb2, ew3, eb3,
                                        alog, rlog, nw2, nb2, rw1, rb1, ws, B);
        const long long tot2 = (long long)B * 4;
        const int g2 = (int)((tot2 + 255) / 256);
        topo_k2<<<g2, 256, 0, stream>>>(ws, nw1, nb1, rw2, rb2, out, B);
    } else {
        const int g = (B + 255) / 256;
        topo_fused<<<g, 256, 0, stream>>>(
            x, ew1, eb1, ew2, eb2, ew3, eb3, nw1, nb1, nw2, nb2,
            alog, rlog, rw1, rb1, rw2, rb2, out, B);
    }
}